// Round 4
// baseline (684.604 us; speedup 1.0000x reference)
//
#include <hip/hip_runtime.h>
#include <hip/hip_bf16.h>
#include <cstdint>
#include <cstddef>

#define N_NODES 100000
#define NFEAT 512
#define NHID 256
#define NCLASS 128
#define K_HOPS 5
#define ALPHA 0.1f

typedef __attribute__((ext_vector_type(8))) short short8v;   // 8 bf16 (4 VGPRs)
typedef __attribute__((ext_vector_type(4))) float f32x4;     // MFMA accumulator

__device__ __forceinline__ unsigned short f2bf(float f) {
    unsigned u = __builtin_bit_cast(unsigned, f);
    u += 0x7FFFu + ((u >> 16) & 1u);      // round-to-nearest-even
    return (unsigned short)(u >> 16);
}
__device__ __forceinline__ float bflo(unsigned u) {
    return __builtin_bit_cast(float, u << 16);
}
__device__ __forceinline__ float bfhi(unsigned u) {
    return __builtin_bit_cast(float, u & 0xFFFF0000u);
}
__device__ __forceinline__ unsigned cvtpk2(float a, float b) {
    unsigned r;
    asm("v_cvt_pk_bf16_f32 %0, %1, %2" : "=v"(r) : "v"(a), "v"(b));
    return r;   // low16 = bf16(a), high16 = bf16(b)
}

// ---------------------------------------------------------------------------
// CSR build: histogram -> hierarchical scan -> scatter (packed int2 metadata)
// ---------------------------------------------------------------------------

__global__ void count_kernel(const int* __restrict__ dst, int* __restrict__ counts, int E) {
    int i = blockIdx.x * blockDim.x + threadIdx.x;
    if (i < E) atomicAdd(&counts[dst[i]], 1);
}

__global__ __launch_bounds__(256) void scan_p1(const int* __restrict__ counts,
                                               int* __restrict__ partial, int n) {
    __shared__ int ws[4];
    int b = blockIdx.x, t = threadIdx.x;
    int base = b * 1024 + t * 4;
    int s = 0;
#pragma unroll
    for (int j = 0; j < 4; ++j) {
        int idx = base + j;
        if (idx < n) s += counts[idx];
    }
#pragma unroll
    for (int off = 32; off; off >>= 1) s += __shfl_xor(s, off, 64);
    if ((t & 63) == 0) ws[t >> 6] = s;
    __syncthreads();
    if (t == 0) partial[b] = ws[0] + ws[1] + ws[2] + ws[3];
}

__global__ __launch_bounds__(128) void scan_p2(int* __restrict__ partial, int nb) {
    __shared__ int s[128];
    int t = threadIdx.x;
    int v = (t < nb) ? partial[t] : 0;
    s[t] = v;
    __syncthreads();
    for (int off = 1; off < 128; off <<= 1) {
        int u = (t >= off) ? s[t - off] : 0;
        __syncthreads();
        s[t] += u;
        __syncthreads();
    }
    if (t < nb) partial[t] = (t == 0) ? 0 : s[t - 1];
}

__global__ __launch_bounds__(256) void scan_p3(const int* __restrict__ counts,
                                               const int* __restrict__ partial,
                                               int* __restrict__ row_ptr,
                                               int* __restrict__ fill, int n) {
    __shared__ int ts[256];
    int b = blockIdx.x, t = threadIdx.x;
    int base = b * 1024 + t * 4;
    int c[4];
#pragma unroll
    for (int j = 0; j < 4; ++j) {
        int idx = base + j;
        c[j] = (idx < n) ? counts[idx] : 0;
    }
    int s = c[0] + c[1] + c[2] + c[3];
    ts[t] = s;
    __syncthreads();
    for (int off = 1; off < 256; off <<= 1) {
        int v = (t >= off) ? ts[t - off] : 0;
        __syncthreads();
        ts[t] += v;
        __syncthreads();
    }
    int pre = partial[b] + ((t == 0) ? 0 : ts[t - 1]);
#pragma unroll
    for (int j = 0; j < 4; ++j) {
        int idx = base + j;
        if (idx < n) {
            row_ptr[idx] = pre;
            fill[idx] = pre;
            if (idx == n - 1) row_ptr[n] = pre + c[j];
            pre += c[j];
        }
    }
}

__global__ void scatter_kernel(const int* __restrict__ src, const int* __restrict__ dst,
                               const float* __restrict__ w, int* __restrict__ fill,
                               int2* __restrict__ epk, int E) {
    int i = blockIdx.x * blockDim.x + threadIdx.x;
    if (i < E) {
        int d = dst[i];
        int pos = atomicAdd(&fill[d], 1);
        int2 m; m.x = src[i]; m.y = __builtin_bit_cast(int, w[i]);
        epk[pos] = m;
    }
}

// ---------------------------------------------------------------------------
// Weight transpose + bf16 convert: Wt[n][k] = bf16(W[k][n])
// ---------------------------------------------------------------------------
__global__ void wtrans_kernel(const float* __restrict__ W, unsigned short* __restrict__ Wt,
                              int K, int N) {
    int idx = blockIdx.x * blockDim.x + threadIdx.x;
    if (idx >= N * K) return;
    int n = idx / K, k = idx - n * K;
    Wt[idx] = f2bf(W[(size_t)k * N + n]);
}

// ---------------------------------------------------------------------------
// Unified MFMA GEMM: C[M][N] = act(A[M][K] @ Wt[N][K]^T + bias), out bf16.
// 128x128 tile, 4 waves, 4x4 16x16x32 frags, BK=32, register prefetch.
// Fragment-major LDS: granule g = subtile*64 + lane6 (16B each) holds
//   [row = (g>>6)*16 + (lane6&15)][k = (lane6>>4)*8 .. +8]
// so frag ds_read_b128 is contiguous 1KB per wave (conflict-free) and
// staging writes are contiguous too.
// AF32=1: A is f32, converted via v_cvt_pk_bf16_f32 during staging.
// ---------------------------------------------------------------------------
template<int K, int N, int RELU, int AF32>
__global__ __launch_bounds__(256) void gemm_mfma(const void* __restrict__ Ain,
                                                 const unsigned short* __restrict__ Wt,
                                                 const float* __restrict__ bias,
                                                 unsigned short* __restrict__ Cout, int M) {
    __shared__ unsigned short As[4096];   // 8KB = 512 granules
    __shared__ unsigned short Bs[4096];
    const int tid = threadIdx.x;
    const int lane = tid & 63;
    const int wv = tid >> 6;
    const int wr = wv >> 1, wc = wv & 1;
    const int brow = blockIdx.y * 128;
    const int bcol = blockIdx.x * 128;
    const float* Af = (const float*)Ain;
    const unsigned short* Ab = (const unsigned short*)Ain;

    // this thread's two granules (g = tid, tid+256): source rows + k offset
    int arow[2], browb[2], kc[2];
#pragma unroll
    for (int i = 0; i < 2; ++i) {
        int g = tid + i * 256, l6 = g & 63;
        int r = (g >> 6) * 16 + (l6 & 15);
        kc[i] = (l6 >> 4) * 8;
        int ra = brow + r; if (ra > M - 1) ra = M - 1;
        arow[i] = ra;
        browb[i] = bcol + r;
    }

    f32x4 acc[4][4];
#pragma unroll
    for (int m = 0; m < 4; ++m)
#pragma unroll
        for (int n = 0; n < 4; ++n) acc[m][n] = f32x4{0.f, 0.f, 0.f, 0.f};

    float4 pa0[2], pa1[2];
    short8v pab[2];
    short8v pb[2];

    // prologue load (k0 = 0)
#pragma unroll
    for (int i = 0; i < 2; ++i) {
        if constexpr (AF32) {
            const float* s = &Af[(size_t)arow[i] * K + kc[i]];
            pa0[i] = *(const float4*)s;
            pa1[i] = *(const float4*)(s + 4);
        } else {
            pab[i] = *(const short8v*)&Ab[(size_t)arow[i] * K + kc[i]];
        }
        pb[i] = *(const short8v*)&Wt[(size_t)browb[i] * K + kc[i]];
    }

    for (int k0 = 0; k0 < K; k0 += 32) {
        // stage current K-chunk from regs
#pragma unroll
        for (int i = 0; i < 2; ++i) {
            int g = tid + i * 256;
            if constexpr (AF32) {
                uint4 u;
                u.x = cvtpk2(pa0[i].x, pa0[i].y);
                u.y = cvtpk2(pa0[i].z, pa0[i].w);
                u.z = cvtpk2(pa1[i].x, pa1[i].y);
                u.w = cvtpk2(pa1[i].z, pa1[i].w);
                *(uint4*)&As[g * 8] = u;
            } else {
                *(short8v*)&As[g * 8] = pab[i];
            }
            *(short8v*)&Bs[g * 8] = pb[i];
        }
        __syncthreads();
        // issue next K-chunk loads early (latency hides under ds_read + MFMA)
        if (k0 + 32 < K) {
#pragma unroll
            for (int i = 0; i < 2; ++i) {
                if constexpr (AF32) {
                    const float* s = &Af[(size_t)arow[i] * K + k0 + 32 + kc[i]];
                    pa0[i] = *(const float4*)s;
                    pa1[i] = *(const float4*)(s + 4);
                } else {
                    pab[i] = *(const short8v*)&Ab[(size_t)arow[i] * K + k0 + 32 + kc[i]];
                }
                pb[i] = *(const short8v*)&Wt[(size_t)browb[i] * K + k0 + 32 + kc[i]];
            }
        }
        short8v a[4], b[4];
#pragma unroll
        for (int m = 0; m < 4; ++m)
            a[m] = *(const short8v*)&As[((wr * 4 + m) * 64 + lane) * 8];
#pragma unroll
        for (int n = 0; n < 4; ++n)
            b[n] = *(const short8v*)&Bs[((wc * 4 + n) * 64 + lane) * 8];
#pragma unroll
        for (int m = 0; m < 4; ++m)
#pragma unroll
            for (int n = 0; n < 4; ++n)
                acc[m][n] = __builtin_amdgcn_mfma_f32_16x16x32_bf16(a[m], b[n], acc[m][n], 0, 0, 0);
        __syncthreads();
    }

#pragma unroll
    for (int n = 0; n < 4; ++n) {
        int colg = bcol + wc * 64 + n * 16 + (lane & 15);
        float bv = bias[colg];
#pragma unroll
        for (int m = 0; m < 4; ++m) {
#pragma unroll
            for (int r = 0; r < 4; ++r) {
                int rowg = brow + wr * 64 + m * 16 + (lane >> 4) * 4 + r;
                if (rowg < M) {
                    float v = acc[m][n][r] + bv;
                    if constexpr (RELU) v = fmaxf(v, 0.f);
                    Cout[(size_t)rowg * N + colg] = f2bf(v);
                }
            }
        }
    }
}

// ---------------------------------------------------------------------------
// One propagation hop (pull over CSR-by-dst), bf16 carry, packed int2 edges.
// One wave per node; lanes preload up to 64 edges' metadata (one 8B load),
// broadcast via readlane. Unroll 8 for deep memory-level parallelism.
// FINAL=1: fuse log-softmax, write f32 to outf.
// ---------------------------------------------------------------------------
template<int FINAL>
__global__ __launch_bounds__(256) void hop_kernel(const unsigned short* __restrict__ carry,
                                                  const unsigned short* __restrict__ c0,
                                                  const int* __restrict__ rp,
                                                  const int2* __restrict__ epk,
                                                  unsigned short* __restrict__ outb,
                                                  float* __restrict__ outf, int nnodes) {
    int node = blockIdx.x * 4 + (threadIdx.x >> 6);
    if (node >= nnodes) return;
    int lane = threadIdx.x & 63;
    int e0 = rp[node], e1 = rp[node + 1];

    float a0x = 0.f, a0y = 0.f, a1x = 0.f, a1y = 0.f;
    float a2x = 0.f, a2y = 0.f, a3x = 0.f, a3y = 0.f;

    for (int eb = e0; eb < e1; eb += 64) {
        int nb = e1 - eb; if (nb > 64) nb = 64;
        int cs = 0, wvi = 0;
        if (lane < nb) {
            int2 m = epk[eb + lane];
            cs = m.x; wvi = m.y;
        }
        int j = 0;
        for (; j + 7 < nb; j += 8) {
            int s0 = __builtin_amdgcn_readlane(cs, j);
            int s1 = __builtin_amdgcn_readlane(cs, j + 1);
            int s2 = __builtin_amdgcn_readlane(cs, j + 2);
            int s3 = __builtin_amdgcn_readlane(cs, j + 3);
            int s4 = __builtin_amdgcn_readlane(cs, j + 4);
            int s5 = __builtin_amdgcn_readlane(cs, j + 5);
            int s6 = __builtin_amdgcn_readlane(cs, j + 6);
            int s7 = __builtin_amdgcn_readlane(cs, j + 7);
            float w0 = __builtin_bit_cast(float, __builtin_amdgcn_readlane(wvi, j));
            float w1 = __builtin_bit_cast(float, __builtin_amdgcn_readlane(wvi, j + 1));
            float w2 = __builtin_bit_cast(float, __builtin_amdgcn_readlane(wvi, j + 2));
            float w3 = __builtin_bit_cast(float, __builtin_amdgcn_readlane(wvi, j + 3));
            float w4 = __builtin_bit_cast(float, __builtin_amdgcn_readlane(wvi, j + 4));
            float w5 = __builtin_bit_cast(float, __builtin_amdgcn_readlane(wvi, j + 5));
            float w6 = __builtin_bit_cast(float, __builtin_amdgcn_readlane(wvi, j + 6));
            float w7 = __builtin_bit_cast(float, __builtin_amdgcn_readlane(wvi, j + 7));
            unsigned u0 = ((const unsigned*)(carry + ((size_t)s0 << 7)))[lane];
            unsigned u1 = ((const unsigned*)(carry + ((size_t)s1 << 7)))[lane];
            unsigned u2 = ((const unsigned*)(carry + ((size_t)s2 << 7)))[lane];
            unsigned u3 = ((const unsigned*)(carry + ((size_t)s3 << 7)))[lane];
            unsigned u4 = ((const unsigned*)(carry + ((size_t)s4 << 7)))[lane];
            unsigned u5 = ((const unsigned*)(carry + ((size_t)s5 << 7)))[lane];
            unsigned u6 = ((const unsigned*)(carry + ((size_t)s6 << 7)))[lane];
            unsigned u7 = ((const unsigned*)(carry + ((size_t)s7 << 7)))[lane];
            a0x = fmaf(w0, bflo(u0), a0x); a0y = fmaf(w0, bfhi(u0), a0y);
            a1x = fmaf(w1, bflo(u1), a1x); a1y = fmaf(w1, bfhi(u1), a1y);
            a2x = fmaf(w2, bflo(u2), a2x); a2y = fmaf(w2, bfhi(u2), a2y);
            a3x = fmaf(w3, bflo(u3), a3x); a3y = fmaf(w3, bfhi(u3), a3y);
            a0x = fmaf(w4, bflo(u4), a0x); a0y = fmaf(w4, bfhi(u4), a0y);
            a1x = fmaf(w5, bflo(u5), a1x); a1y = fmaf(w5, bfhi(u5), a1y);
            a2x = fmaf(w6, bflo(u6), a2x); a2y = fmaf(w6, bfhi(u6), a2y);
            a3x = fmaf(w7, bflo(u7), a3x); a3y = fmaf(w7, bfhi(u7), a3y);
        }
        for (; j + 3 < nb; j += 4) {
            int s0 = __builtin_amdgcn_readlane(cs, j);
            int s1 = __builtin_amdgcn_readlane(cs, j + 1);
            int s2 = __builtin_amdgcn_readlane(cs, j + 2);
            int s3 = __builtin_amdgcn_readlane(cs, j + 3);
            float w0 = __builtin_bit_cast(float, __builtin_amdgcn_readlane(wvi, j));
            float w1 = __builtin_bit_cast(float, __builtin_amdgcn_readlane(wvi, j + 1));
            float w2 = __builtin_bit_cast(float, __builtin_amdgcn_readlane(wvi, j + 2));
            float w3 = __builtin_bit_cast(float, __builtin_amdgcn_readlane(wvi, j + 3));
            unsigned u0 = ((const unsigned*)(carry + ((size_t)s0 << 7)))[lane];
            unsigned u1 = ((const unsigned*)(carry + ((size_t)s1 << 7)))[lane];
            unsigned u2 = ((const unsigned*)(carry + ((size_t)s2 << 7)))[lane];
            unsigned u3 = ((const unsigned*)(carry + ((size_t)s3 << 7)))[lane];
            a0x = fmaf(w0, bflo(u0), a0x); a0y = fmaf(w0, bfhi(u0), a0y);
            a1x = fmaf(w1, bflo(u1), a1x); a1y = fmaf(w1, bfhi(u1), a1y);
            a2x = fmaf(w2, bflo(u2), a2x); a2y = fmaf(w2, bfhi(u2), a2y);
            a3x = fmaf(w3, bflo(u3), a3x); a3y = fmaf(w3, bfhi(u3), a3y);
        }
        for (; j < nb; ++j) {
            int s0 = __builtin_amdgcn_readlane(cs, j);
            float w0 = __builtin_bit_cast(float, __builtin_amdgcn_readlane(wvi, j));
            unsigned u0 = ((const unsigned*)(carry + ((size_t)s0 << 7)))[lane];
            a0x = fmaf(w0, bflo(u0), a0x); a0y = fmaf(w0, bfhi(u0), a0y);
        }
    }

    unsigned ux = ((const unsigned*)(c0 + ((size_t)node << 7)))[lane];
    float vx = (1.f - ALPHA) * (a0x + a1x + a2x + a3x) + ALPHA * bflo(ux);
    float vy = (1.f - ALPHA) * (a0y + a1y + a2y + a3y) + ALPHA * bfhi(ux);

    if (FINAL) {
        float mx = fmaxf(vx, vy);
#pragma unroll
        for (int off = 32; off; off >>= 1) mx = fmaxf(mx, __shfl_xor(mx, off, 64));
        float se = __expf(vx - mx) + __expf(vy - mx);
#pragma unroll
        for (int off = 32; off; off >>= 1) se += __shfl_xor(se, off, 64);
        float l = mx + __logf(se);
        float2 o; o.x = vx - l; o.y = vy - l;
        ((float2*)(outf + ((size_t)node << 7)))[lane] = o;
    } else {
        unsigned o = (unsigned)f2bf(vx) | ((unsigned)f2bf(vy) << 16);
        ((unsigned*)(outb + ((size_t)node << 7)))[lane] = o;
    }
}

// ---------------------------------------------------------------------------

extern "C" void kernel_launch(void* const* d_in, const int* in_sizes, int n_in,
                              void* d_out, int out_size, void* d_ws, size_t ws_size,
                              hipStream_t stream) {
    const float* x   = (const float*)d_in[0];
    const int*   ei  = (const int*)d_in[1];
    const float* ew  = (const float*)d_in[2];
    const float* W1  = (const float*)d_in[3];
    const float* b1  = (const float*)d_in[4];
    const float* W2  = (const float*)d_in[5];
    const float* b2  = (const float*)d_in[6];
    float* outp = (float*)d_out;

    const int E = in_sizes[1] / 2;
    const int Nn = N_NODES;
    const int* srcv = ei;
    const int* dstv = ei + E;
    const size_t NC = (size_t)Nn * NCLASS;   // 12.8M elements

    // workspace layout (16B-aligned buffers)
    unsigned short* c0  = (unsigned short*)d_ws;    // bf16 x0 copy     [NC]
    unsigned short* A16 = c0 + NC;                  // ping             [NC]
    unsigned short* B16 = A16 + NC;                 // pong             [NC]
    unsigned short* hb  = A16;                      // H bf16 overlay (Nn*NHID = 2*NC, dead before hops)
    unsigned short* w1t = B16 + NC;                 // 256x512
    unsigned short* w2t = w1t + NHID * NFEAT;       // 128x256
    int* row_ptr = (int*)(w2t + NCLASS * NHID);     // Nn+1
    int* fill    = row_ptr + (Nn + 1);              // Nn (counts)
    int* partial = fill + Nn;                       // 128
    int2* epk    = (int2*)(partial + 128);          // E packed {src, w}

    const int NB = (Nn + 1023) / 1024;              // 98 scan blocks

    // ---- CSR build ----
    hipMemsetAsync(fill, 0, (size_t)Nn * sizeof(int), stream);
    count_kernel<<<(E + 255) / 256, 256, 0, stream>>>(dstv, fill, E);
    scan_p1<<<NB, 256, 0, stream>>>(fill, partial, Nn);
    scan_p2<<<1, 128, 0, stream>>>(partial, NB);
    scan_p3<<<NB, 256, 0, stream>>>(fill, partial, row_ptr, fill, Nn);
    scatter_kernel<<<(E + 255) / 256, 256, 0, stream>>>(srcv, dstv, ew, fill, epk, E);

    // ---- weight prep ----
    wtrans_kernel<<<(NHID * NFEAT + 255) / 256, 256, 0, stream>>>(W1, w1t, NFEAT, NHID);
    wtrans_kernel<<<(NCLASS * NHID + 255) / 256, 256, 0, stream>>>(W2, w2t, NHID, NCLASS);

    // ---- MLP (bf16 MFMA) ----
    {
        dim3 g1(NHID / 128, (Nn + 127) / 128);
        gemm_mfma<NFEAT, NHID, 1, 1><<<g1, 256, 0, stream>>>(x, w1t, b1, hb, Nn);
        dim3 g2(NCLASS / 128, (Nn + 127) / 128);
        gemm_mfma<NHID, NCLASS, 0, 0><<<g2, 256, 0, stream>>>(hb, w2t, b2, c0, Nn);
    }

    // ---- K_HOPS propagation (bf16 carry), ping-pong; last hop fuses softmax ----
    int grid = (Nn + 3) / 4;
    const unsigned short* carry = c0;
    unsigned short* dsts[2] = {A16, B16};
    for (int k = 0; k < K_HOPS - 1; ++k) {
        unsigned short* o = dsts[k & 1];
        hop_kernel<0><<<grid, 256, 0, stream>>>(carry, c0, row_ptr, epk, o, nullptr, Nn);
        carry = o;
    }
    hop_kernel<1><<<grid, 256, 0, stream>>>(carry, c0, row_ptr, epk, nullptr, outp, Nn);
}

// Round 5
// 666.598 us; speedup vs baseline: 1.0270x; 1.0270x over previous
//
#include <hip/hip_runtime.h>
#include <hip/hip_bf16.h>
#include <cstdint>
#include <cstddef>

#define N_NODES 100000
#define NFEAT 512
#define NHID 256
#define NCLASS 128
#define K_HOPS 5
#define ALPHA 0.1f

typedef __attribute__((ext_vector_type(8))) short short8v;   // 8 bf16 (4 VGPRs)
typedef __attribute__((ext_vector_type(4))) float f32x4;     // MFMA accumulator

__device__ __forceinline__ unsigned short f2bf(float f) {
    unsigned u = __builtin_bit_cast(unsigned, f);
    u += 0x7FFFu + ((u >> 16) & 1u);      // round-to-nearest-even
    return (unsigned short)(u >> 16);
}
__device__ __forceinline__ float bflo(unsigned u) {
    return __builtin_bit_cast(float, u << 16);
}
__device__ __forceinline__ float bfhi(unsigned u) {
    return __builtin_bit_cast(float, u & 0xFFFF0000u);
}
__device__ __forceinline__ unsigned cvtpk2(float a, float b) {
    unsigned r;
    asm("v_cvt_pk_bf16_f32 %0, %1, %2" : "=v"(r) : "v"(a), "v"(b));
    return r;   // low16 = bf16(a), high16 = bf16(b)
}
__device__ __forceinline__ void gload_lds16(const void* g, void* l) {
    __builtin_amdgcn_global_load_lds((const __attribute__((address_space(1))) void*)g,
                                     (__attribute__((address_space(3))) void*)l, 16, 0, 0);
}

// ---------------------------------------------------------------------------
// CSR build: histogram -> hierarchical scan -> scatter (packed int2 metadata)
// ---------------------------------------------------------------------------

__global__ void count_kernel(const int* __restrict__ dst, int* __restrict__ counts, int E) {
    int i = blockIdx.x * blockDim.x + threadIdx.x;
    if (i < E) atomicAdd(&counts[dst[i]], 1);
}

__global__ __launch_bounds__(256) void scan_p1(const int* __restrict__ counts,
                                               int* __restrict__ partial, int n) {
    __shared__ int ws[4];
    int b = blockIdx.x, t = threadIdx.x;
    int base = b * 1024 + t * 4;
    int s = 0;
#pragma unroll
    for (int j = 0; j < 4; ++j) {
        int idx = base + j;
        if (idx < n) s += counts[idx];
    }
#pragma unroll
    for (int off = 32; off; off >>= 1) s += __shfl_xor(s, off, 64);
    if ((t & 63) == 0) ws[t >> 6] = s;
    __syncthreads();
    if (t == 0) partial[b] = ws[0] + ws[1] + ws[2] + ws[3];
}

__global__ __launch_bounds__(128) void scan_p2(int* __restrict__ partial, int nb) {
    __shared__ int s[128];
    int t = threadIdx.x;
    int v = (t < nb) ? partial[t] : 0;
    s[t] = v;
    __syncthreads();
    for (int off = 1; off < 128; off <<= 1) {
        int u = (t >= off) ? s[t - off] : 0;
        __syncthreads();
        s[t] += u;
        __syncthreads();
    }
    if (t < nb) partial[t] = (t == 0) ? 0 : s[t - 1];
}

__global__ __launch_bounds__(256) void scan_p3(const int* __restrict__ counts,
                                               const int* __restrict__ partial,
                                               int* __restrict__ row_ptr,
                                               int* __restrict__ fill, int n) {
    __shared__ int ts[256];
    int b = blockIdx.x, t = threadIdx.x;
    int base = b * 1024 + t * 4;
    int c[4];
#pragma unroll
    for (int j = 0; j < 4; ++j) {
        int idx = base + j;
        c[j] = (idx < n) ? counts[idx] : 0;
    }
    int s = c[0] + c[1] + c[2] + c[3];
    ts[t] = s;
    __syncthreads();
    for (int off = 1; off < 256; off <<= 1) {
        int v = (t >= off) ? ts[t - off] : 0;
        __syncthreads();
        ts[t] += v;
        __syncthreads();
    }
    int pre = partial[b] + ((t == 0) ? 0 : ts[t - 1]);
#pragma unroll
    for (int j = 0; j < 4; ++j) {
        int idx = base + j;
        if (idx < n) {
            row_ptr[idx] = pre;
            fill[idx] = pre;
            if (idx == n - 1) row_ptr[n] = pre + c[j];
            pre += c[j];
        }
    }
}

__global__ void scatter_kernel(const int* __restrict__ src, const int* __restrict__ dst,
                               const float* __restrict__ w, int* __restrict__ fill,
                               int2* __restrict__ epk, int E) {
    int i = blockIdx.x * blockDim.x + threadIdx.x;
    if (i < E) {
        int d = dst[i];
        int pos = atomicAdd(&fill[d], 1);
        int2 m; m.x = src[i]; m.y = __builtin_bit_cast(int, w[i]);
        epk[pos] = m;
    }
}

// ---------------------------------------------------------------------------
// Weight transpose + bf16 convert: Wt[n][k] = bf16(W[k][n])
// ---------------------------------------------------------------------------
__global__ void wtrans_kernel(const float* __restrict__ W, unsigned short* __restrict__ Wt,
                              int K, int N) {
    int idx = blockIdx.x * blockDim.x + threadIdx.x;
    if (idx >= N * K) return;
    int n = idx / K, k = idx - n * K;
    Wt[idx] = f2bf(W[(size_t)k * N + n]);
}

// ---------------------------------------------------------------------------
// MFMA GEMM, global_load_lds double-buffered 2-phase.
// C[M][N] = act(A[M][K] @ Wt[N][K]^T + bias), out bf16.
// 128x128 tile, 4 waves, 4x4 16x16x32 frags, BK=32.
// Fragment-major LDS (16B granules), dest of each global_load_lds is
// uniform_base + lane*16 (linear), per-lane global source:
//   bf16 plane: granule g = sub*64 + lane -> T[row=sub*16+(lane&15)][k=(lane>>4)*8..+8]
//   f32 A tile: two planes (k-halves): g = half*512 + sub*64 + lane ->
//               X[row=sub*16+(lane&15)][k=(lane>>4)*8 + half*4 ..+4]
// Frag ds_read_b128 is lane-linear -> conflict-free. AF32 converts at
// consume time via v_cvt_pk_bf16_f32 (VALU is idle).
// ---------------------------------------------------------------------------
template<int K, int N, int RELU, int AF32>
__global__ __launch_bounds__(256) void gemm_mfma(const void* __restrict__ Ain,
                                                 const unsigned short* __restrict__ Wt,
                                                 const float* __restrict__ bias,
                                                 unsigned short* __restrict__ Cout, int M) {
    extern __shared__ char smem[];
    constexpr int ABYTES = AF32 ? 16384 : 8192;   // per A buffer
    constexpr int ASTEP  = AF32 ? 128 : 64;       // bytes per row per K-step
    constexpr int NCA    = AF32 ? 4 : 2;          // A chunks per wave
    char* Abase = smem;
    char* Bbase = smem + 2 * ABYTES;

    const int tid = threadIdx.x;
    const int lane = tid & 63;
    const int wv = tid >> 6;
    const int wr = wv >> 1, wc = wv & 1;
    const int brow = blockIdx.y * 128;
    const int bcol = blockIdx.x * 128;
    const float* Af = (const float*)Ain;
    const unsigned short* Ab = (const unsigned short*)Ain;

    // per-lane global sources for this wave's staging chunks (k0 = 0)
    const char* asrc[NCA];
    int aci[NCA];
#pragma unroll
    for (int c = 0; c < NCA; ++c) {
        int ci = wv + c * 4;
        aci[c] = ci;
        int ms = AF32 ? (ci & 7) : ci;
        int koff = (lane >> 4) * 8 + (AF32 ? (ci >> 3) * 4 : 0);
        int ar = brow + ms * 16 + (lane & 15); if (ar > M - 1) ar = M - 1;
        asrc[c] = AF32 ? (const char*)&Af[(size_t)ar * K + koff]
                       : (const char*)&Ab[(size_t)ar * K + koff];
    }
    const char* bsrc[2];
#pragma unroll
    for (int c = 0; c < 2; ++c) {
        int ci = wv + c * 4;
        int bc = bcol + ci * 16 + (lane & 15);
        bsrc[c] = (const char*)&Wt[(size_t)bc * K + (lane >> 4) * 8];
    }

    f32x4 acc[4][4];
#pragma unroll
    for (int m = 0; m < 4; ++m)
#pragma unroll
        for (int n = 0; n < 4; ++n) acc[m][n] = f32x4{0.f, 0.f, 0.f, 0.f};

    auto stage = [&](int buf, int step) {
        char* la = Abase + buf * ABYTES;
        char* lb = Bbase + buf * 8192;
#pragma unroll
        for (int c = 0; c < NCA; ++c)
            gload_lds16(asrc[c] + (size_t)step * ASTEP, la + aci[c] * 1024);
#pragma unroll
        for (int c = 0; c < 2; ++c)
            gload_lds16(bsrc[c] + (size_t)step * 64, lb + (wv + c * 4) * 1024);
    };

    constexpr int NSTEP = K / 32;
    int cur = 0;
    stage(0, 0);
    asm volatile("s_waitcnt vmcnt(0)" ::: "memory");
    __syncthreads();

    for (int s = 0; s < NSTEP; ++s) {
        if (s + 1 < NSTEP) stage(cur ^ 1, s + 1);   // async loads in flight under compute

        short8v a[4], b[4];
        if constexpr (AF32) {
            const float* Asf = (const float*)(Abase + cur * ABYTES);
#pragma unroll
            for (int m = 0; m < 4; ++m) {
                int g = (wr * 4 + m) * 64 + lane;
                f32x4 lo = *(const f32x4*)&Asf[g * 4];
                f32x4 hi = *(const f32x4*)&Asf[(512 + g) * 4];
                uint4 u;
                u.x = cvtpk2(lo[0], lo[1]); u.y = cvtpk2(lo[2], lo[3]);
                u.z = cvtpk2(hi[0], hi[1]); u.w = cvtpk2(hi[2], hi[3]);
                a[m] = __builtin_bit_cast(short8v, u);
            }
        } else {
            const unsigned short* As16 = (const unsigned short*)(Abase + cur * ABYTES);
#pragma unroll
            for (int m = 0; m < 4; ++m)
                a[m] = *(const short8v*)&As16[((wr * 4 + m) * 64 + lane) * 8];
        }
        const unsigned short* Bs16 = (const unsigned short*)(Bbase + cur * 8192);
#pragma unroll
        for (int n = 0; n < 4; ++n)
            b[n] = *(const short8v*)&Bs16[((wc * 4 + n) * 64 + lane) * 8];

#pragma unroll
        for (int m = 0; m < 4; ++m)
#pragma unroll
            for (int n = 0; n < 4; ++n)
                acc[m][n] = __builtin_amdgcn_mfma_f32_16x16x32_bf16(a[m], b[n], acc[m][n], 0, 0, 0);

        asm volatile("s_waitcnt vmcnt(0)" ::: "memory");
        __syncthreads();
        cur ^= 1;
    }

#pragma unroll
    for (int n = 0; n < 4; ++n) {
        int colg = bcol + wc * 64 + n * 16 + (lane & 15);
        float bv = bias[colg];
#pragma unroll
        for (int m = 0; m < 4; ++m) {
#pragma unroll
            for (int r = 0; r < 4; ++r) {
                int rowg = brow + wr * 64 + m * 16 + (lane >> 4) * 4 + r;
                if (rowg < M) {
                    float v = acc[m][n][r] + bv;
                    if constexpr (RELU) v = fmaxf(v, 0.f);
                    Cout[(size_t)rowg * N + colg] = f2bf(v);
                }
            }
        }
    }
}

// ---------------------------------------------------------------------------
// One propagation hop (pull over CSR-by-dst), bf16 carry, packed int2 edges.
// One wave per node; lanes preload up to 64 edges' metadata (one 8B load),
// broadcast via readlane. Unroll 8 for deep memory-level parallelism.
// FINAL=1: fuse log-softmax, write f32 to outf.
// ---------------------------------------------------------------------------
template<int FINAL>
__global__ __launch_bounds__(256) void hop_kernel(const unsigned short* __restrict__ carry,
                                                  const unsigned short* __restrict__ c0,
                                                  const int* __restrict__ rp,
                                                  const int2* __restrict__ epk,
                                                  unsigned short* __restrict__ outb,
                                                  float* __restrict__ outf, int nnodes) {
    int node = blockIdx.x * 4 + (threadIdx.x >> 6);
    if (node >= nnodes) return;
    int lane = threadIdx.x & 63;
    int e0 = rp[node], e1 = rp[node + 1];

    float a0x = 0.f, a0y = 0.f, a1x = 0.f, a1y = 0.f;
    float a2x = 0.f, a2y = 0.f, a3x = 0.f, a3y = 0.f;

    for (int eb = e0; eb < e1; eb += 64) {
        int nb = e1 - eb; if (nb > 64) nb = 64;
        int cs = 0, wvi = 0;
        if (lane < nb) {
            int2 m = epk[eb + lane];
            cs = m.x; wvi = m.y;
        }
        int j = 0;
        for (; j + 7 < nb; j += 8) {
            int s0 = __builtin_amdgcn_readlane(cs, j);
            int s1 = __builtin_amdgcn_readlane(cs, j + 1);
            int s2 = __builtin_amdgcn_readlane(cs, j + 2);
            int s3 = __builtin_amdgcn_readlane(cs, j + 3);
            int s4 = __builtin_amdgcn_readlane(cs, j + 4);
            int s5 = __builtin_amdgcn_readlane(cs, j + 5);
            int s6 = __builtin_amdgcn_readlane(cs, j + 6);
            int s7 = __builtin_amdgcn_readlane(cs, j + 7);
            float w0 = __builtin_bit_cast(float, __builtin_amdgcn_readlane(wvi, j));
            float w1 = __builtin_bit_cast(float, __builtin_amdgcn_readlane(wvi, j + 1));
            float w2 = __builtin_bit_cast(float, __builtin_amdgcn_readlane(wvi, j + 2));
            float w3 = __builtin_bit_cast(float, __builtin_amdgcn_readlane(wvi, j + 3));
            float w4 = __builtin_bit_cast(float, __builtin_amdgcn_readlane(wvi, j + 4));
            float w5 = __builtin_bit_cast(float, __builtin_amdgcn_readlane(wvi, j + 5));
            float w6 = __builtin_bit_cast(float, __builtin_amdgcn_readlane(wvi, j + 6));
            float w7 = __builtin_bit_cast(float, __builtin_amdgcn_readlane(wvi, j + 7));
            unsigned u0 = ((const unsigned*)(carry + ((size_t)s0 << 7)))[lane];
            unsigned u1 = ((const unsigned*)(carry + ((size_t)s1 << 7)))[lane];
            unsigned u2 = ((const unsigned*)(carry + ((size_t)s2 << 7)))[lane];
            unsigned u3 = ((const unsigned*)(carry + ((size_t)s3 << 7)))[lane];
            unsigned u4 = ((const unsigned*)(carry + ((size_t)s4 << 7)))[lane];
            unsigned u5 = ((const unsigned*)(carry + ((size_t)s5 << 7)))[lane];
            unsigned u6 = ((const unsigned*)(carry + ((size_t)s6 << 7)))[lane];
            unsigned u7 = ((const unsigned*)(carry + ((size_t)s7 << 7)))[lane];
            a0x = fmaf(w0, bflo(u0), a0x); a0y = fmaf(w0, bfhi(u0), a0y);
            a1x = fmaf(w1, bflo(u1), a1x); a1y = fmaf(w1, bfhi(u1), a1y);
            a2x = fmaf(w2, bflo(u2), a2x); a2y = fmaf(w2, bfhi(u2), a2y);
            a3x = fmaf(w3, bflo(u3), a3x); a3y = fmaf(w3, bfhi(u3), a3y);
            a0x = fmaf(w4, bflo(u4), a0x); a0y = fmaf(w4, bfhi(u4), a0y);
            a1x = fmaf(w5, bflo(u5), a1x); a1y = fmaf(w5, bfhi(u5), a1y);
            a2x = fmaf(w6, bflo(u6), a2x); a2y = fmaf(w6, bfhi(u6), a2y);
            a3x = fmaf(w7, bflo(u7), a3x); a3y = fmaf(w7, bfhi(u7), a3y);
        }
        for (; j + 3 < nb; j += 4) {
            int s0 = __builtin_amdgcn_readlane(cs, j);
            int s1 = __builtin_amdgcn_readlane(cs, j + 1);
            int s2 = __builtin_amdgcn_readlane(cs, j + 2);
            int s3 = __builtin_amdgcn_readlane(cs, j + 3);
            float w0 = __builtin_bit_cast(float, __builtin_amdgcn_readlane(wvi, j));
            float w1 = __builtin_bit_cast(float, __builtin_amdgcn_readlane(wvi, j + 1));
            float w2 = __builtin_bit_cast(float, __builtin_amdgcn_readlane(wvi, j + 2));
            float w3 = __builtin_bit_cast(float, __builtin_amdgcn_readlane(wvi, j + 3));
            unsigned u0 = ((const unsigned*)(carry + ((size_t)s0 << 7)))[lane];
            unsigned u1 = ((const unsigned*)(carry + ((size_t)s1 << 7)))[lane];
            unsigned u2 = ((const unsigned*)(carry + ((size_t)s2 << 7)))[lane];
            unsigned u3 = ((const unsigned*)(carry + ((size_t)s3 << 7)))[lane];
            a0x = fmaf(w0, bflo(u0), a0x); a0y = fmaf(w0, bfhi(u0), a0y);
            a1x = fmaf(w1, bflo(u1), a1x); a1y = fmaf(w1, bfhi(u1), a1y);
            a2x = fmaf(w2, bflo(u2), a2x); a2y = fmaf(w2, bfhi(u2), a2y);
            a3x = fmaf(w3, bflo(u3), a3x); a3y = fmaf(w3, bfhi(u3), a3y);
        }
        for (; j < nb; ++j) {
            int s0 = __builtin_amdgcn_readlane(cs, j);
            float w0 = __builtin_bit_cast(float, __builtin_amdgcn_readlane(wvi, j));
            unsigned u0 = ((const unsigned*)(carry + ((size_t)s0 << 7)))[lane];
            a0x = fmaf(w0, bflo(u0), a0x); a0y = fmaf(w0, bfhi(u0), a0y);
        }
    }

    unsigned ux = ((const unsigned*)(c0 + ((size_t)node << 7)))[lane];
    float vx = (1.f - ALPHA) * (a0x + a1x + a2x + a3x) + ALPHA * bflo(ux);
    float vy = (1.f - ALPHA) * (a0y + a1y + a2y + a3y) + ALPHA * bfhi(ux);

    if (FINAL) {
        float mx = fmaxf(vx, vy);
#pragma unroll
        for (int off = 32; off; off >>= 1) mx = fmaxf(mx, __shfl_xor(mx, off, 64));
        float se = __expf(vx - mx) + __expf(vy - mx);
#pragma unroll
        for (int off = 32; off; off >>= 1) se += __shfl_xor(se, off, 64);
        float l = mx + __logf(se);
        float2 o; o.x = vx - l; o.y = vy - l;
        ((float2*)(outf + ((size_t)node << 7)))[lane] = o;
    } else {
        unsigned o = (unsigned)f2bf(vx) | ((unsigned)f2bf(vy) << 16);
        ((unsigned*)(outb + ((size_t)node << 7)))[lane] = o;
    }
}

// ---------------------------------------------------------------------------

extern "C" void kernel_launch(void* const* d_in, const int* in_sizes, int n_in,
                              void* d_out, int out_size, void* d_ws, size_t ws_size,
                              hipStream_t stream) {
    const float* x   = (const float*)d_in[0];
    const int*   ei  = (const int*)d_in[1];
    const float* ew  = (const float*)d_in[2];
    const float* W1  = (const float*)d_in[3];
    const float* b1  = (const float*)d_in[4];
    const float* W2  = (const float*)d_in[5];
    const float* b2  = (const float*)d_in[6];
    float* outp = (float*)d_out;

    const int E = in_sizes[1] / 2;
    const int Nn = N_NODES;
    const int* srcv = ei;
    const int* dstv = ei + E;
    const size_t NC = (size_t)Nn * NCLASS;   // 12.8M elements

    // workspace layout (16B-aligned buffers)
    unsigned short* c0  = (unsigned short*)d_ws;    // bf16 x0 copy     [NC]
    unsigned short* A16 = c0 + NC;                  // ping             [NC]
    unsigned short* B16 = A16 + NC;                 // pong             [NC]
    unsigned short* hb  = A16;                      // H bf16 overlay (Nn*NHID = 2*NC, dead before hops)
    unsigned short* w1t = B16 + NC;                 // 256x512
    unsigned short* w2t = w1t + NHID * NFEAT;       // 128x256
    int* row_ptr = (int*)(w2t + NCLASS * NHID);     // Nn+1
    int* fill    = row_ptr + (Nn + 1);              // Nn (counts)
    int* partial = fill + Nn;                       // 128
    int2* epk    = (int2*)(partial + 128);          // E packed {src, w}

    const int NB = (Nn + 1023) / 1024;              // 98 scan blocks

    // ---- CSR build ----
    hipMemsetAsync(fill, 0, (size_t)Nn * sizeof(int), stream);
    count_kernel<<<(E + 255) / 256, 256, 0, stream>>>(dstv, fill, E);
    scan_p1<<<NB, 256, 0, stream>>>(fill, partial, Nn);
    scan_p2<<<1, 128, 0, stream>>>(partial, NB);
    scan_p3<<<NB, 256, 0, stream>>>(fill, partial, row_ptr, fill, Nn);
    scatter_kernel<<<(E + 255) / 256, 256, 0, stream>>>(srcv, dstv, ew, fill, epk, E);

    // ---- weight prep ----
    wtrans_kernel<<<(NHID * NFEAT + 255) / 256, 256, 0, stream>>>(W1, w1t, NFEAT, NHID);
    wtrans_kernel<<<(NCLASS * NHID + 255) / 256, 256, 0, stream>>>(W2, w2t, NHID, NCLASS);

    // ---- MLP (bf16 MFMA, global_load_lds 2-phase) ----
    {
        dim3 g1(NHID / 128, (Nn + 127) / 128);
        gemm_mfma<NFEAT, NHID, 1, 1><<<g1, 256, 49152, stream>>>(x, w1t, b1, hb, Nn);
        dim3 g2(NCLASS / 128, (Nn + 127) / 128);
        gemm_mfma<NHID, NCLASS, 0, 0><<<g2, 256, 32768, stream>>>(hb, w2t, b2, c0, Nn);
    }

    // ---- K_HOPS propagation (bf16 carry), ping-pong; last hop fuses softmax ----
    int grid = (Nn + 3) / 4;
    const unsigned short* carry = c0;
    unsigned short* dsts[2] = {A16, B16};
    for (int k = 0; k < K_HOPS - 1; ++k) {
        unsigned short* o = dsts[k & 1];
        hop_kernel<0><<<grid, 256, 0, stream>>>(carry, c0, row_ptr, epk, o, nullptr, Nn);
        carry = o;
    }
    hop_kernel<1><<<grid, 256, 0, stream>>>(carry, c0, row_ptr, epk, nullptr, outp, Nn);
}

// Round 6
// 640.383 us; speedup vs baseline: 1.0691x; 1.0409x over previous
//
#include <hip/hip_runtime.h>
#include <hip/hip_bf16.h>
#include <cstdint>
#include <cstddef>

#define N_NODES 100000
#define NFEAT 512
#define NHID 256
#define NCLASS 128
#define K_HOPS 5
#define ALPHA 0.1f

typedef __attribute__((ext_vector_type(8))) short short8v;   // 8 bf16 (4 VGPRs)
typedef __attribute__((ext_vector_type(4))) float f32x4;     // MFMA accumulator

__device__ __forceinline__ unsigned short f2bf(float f) {
    unsigned u = __builtin_bit_cast(unsigned, f);
    u += 0x7FFFu + ((u >> 16) & 1u);      // round-to-nearest-even
    return (unsigned short)(u >> 16);
}
__device__ __forceinline__ float bflo(unsigned u) {
    return __builtin_bit_cast(float, u << 16);
}
__device__ __forceinline__ float bfhi(unsigned u) {
    return __builtin_bit_cast(float, u & 0xFFFF0000u);
}
__device__ __forceinline__ unsigned cvtpk2(float a, float b) {
    unsigned r;
    asm("v_cvt_pk_bf16_f32 %0, %1, %2" : "=v"(r) : "v"(a), "v"(b));
    return r;   // low16 = bf16(a), high16 = bf16(b)
}
__device__ __forceinline__ void gload_lds16(const void* g, void* l) {
    __builtin_amdgcn_global_load_lds((const __attribute__((address_space(1))) void*)g,
                                     (__attribute__((address_space(3))) void*)l, 16, 0, 0);
}

// ---------------------------------------------------------------------------
// CSR build: histogram -> hierarchical scan -> scatter (packed int2 metadata)
// ---------------------------------------------------------------------------

__global__ void count_kernel(const int* __restrict__ dst, int* __restrict__ counts, int E) {
    int i = blockIdx.x * blockDim.x + threadIdx.x;
    if (i < E) atomicAdd(&counts[dst[i]], 1);
}

__global__ __launch_bounds__(256) void scan_p1(const int* __restrict__ counts,
                                               int* __restrict__ partial, int n) {
    __shared__ int ws[4];
    int b = blockIdx.x, t = threadIdx.x;
    int base = b * 1024 + t * 4;
    int s = 0;
#pragma unroll
    for (int j = 0; j < 4; ++j) {
        int idx = base + j;
        if (idx < n) s += counts[idx];
    }
#pragma unroll
    for (int off = 32; off; off >>= 1) s += __shfl_xor(s, off, 64);
    if ((t & 63) == 0) ws[t >> 6] = s;
    __syncthreads();
    if (t == 0) partial[b] = ws[0] + ws[1] + ws[2] + ws[3];
}

__global__ __launch_bounds__(128) void scan_p2(int* __restrict__ partial, int nb) {
    __shared__ int s[128];
    int t = threadIdx.x;
    int v = (t < nb) ? partial[t] : 0;
    s[t] = v;
    __syncthreads();
    for (int off = 1; off < 128; off <<= 1) {
        int u = (t >= off) ? s[t - off] : 0;
        __syncthreads();
        s[t] += u;
        __syncthreads();
    }
    if (t < nb) partial[t] = (t == 0) ? 0 : s[t - 1];
}

__global__ __launch_bounds__(256) void scan_p3(const int* __restrict__ counts,
                                               const int* __restrict__ partial,
                                               int* __restrict__ row_ptr,
                                               int* __restrict__ fill, int n) {
    __shared__ int ts[256];
    int b = blockIdx.x, t = threadIdx.x;
    int base = b * 1024 + t * 4;
    int c[4];
#pragma unroll
    for (int j = 0; j < 4; ++j) {
        int idx = base + j;
        c[j] = (idx < n) ? counts[idx] : 0;
    }
    int s = c[0] + c[1] + c[2] + c[3];
    ts[t] = s;
    __syncthreads();
    for (int off = 1; off < 256; off <<= 1) {
        int v = (t >= off) ? ts[t - off] : 0;
        __syncthreads();
        ts[t] += v;
        __syncthreads();
    }
    int pre = partial[b] + ((t == 0) ? 0 : ts[t - 1]);
#pragma unroll
    for (int j = 0; j < 4; ++j) {
        int idx = base + j;
        if (idx < n) {
            row_ptr[idx] = pre;
            fill[idx] = pre;
            if (idx == n - 1) row_ptr[n] = pre + c[j];
            pre += c[j];
        }
    }
}

__global__ void scatter_kernel(const int* __restrict__ src, const int* __restrict__ dst,
                               const float* __restrict__ w, int* __restrict__ fill,
                               int2* __restrict__ epk, int E) {
    int i = blockIdx.x * blockDim.x + threadIdx.x;
    if (i < E) {
        int d = dst[i];
        int pos = atomicAdd(&fill[d], 1);
        int2 m; m.x = src[i]; m.y = __builtin_bit_cast(int, w[i]);
        epk[pos] = m;
    }
}

// ---------------------------------------------------------------------------
// Weight transpose + bf16 convert: Wt[n][k] = bf16(W[k][n])
// ---------------------------------------------------------------------------
__global__ void wtrans_kernel(const float* __restrict__ W, unsigned short* __restrict__ Wt,
                              int K, int N) {
    int idx = blockIdx.x * blockDim.x + threadIdx.x;
    if (idx >= N * K) return;
    int n = idx / K, k = idx - n * K;
    Wt[idx] = f2bf(W[(size_t)k * N + n]);
}

// ---------------------------------------------------------------------------
// GEMM layer 1, deep-pipelined: Hb[M][256] = relu(X[M][512] @ W1t[256][512]^T + b1)
// Tile 128x256 (full N -> X read exactly once), 512 threads (8 waves, 2x4),
// BK=32, NBUF=4, depth-2 prefetch, counted vmcnt + raw s_barrier (never
// drains to 0 in the main loop). A staged f32 (two k-half planes), converted
// at consume via v_cvt_pk_bf16_f32. All LDS granules 16B, dest = uniform
// base (+lane*16 by HW), frag ds_read_b128 lane-linear -> conflict-free.
// Per-wave loads/stage = 4 (2 A + 2 B) -> vmcnt(8)/(4)/(0).
// ---------------------------------------------------------------------------
__global__ __launch_bounds__(512) void gemm1_pipe(const float* __restrict__ X,
                                                  const unsigned short* __restrict__ W1t,
                                                  const float* __restrict__ b1,
                                                  unsigned short* __restrict__ Hb, int M) {
    __shared__ char smem[131072];          // 4x16KB A (f32) + 4x16KB B (bf16)
    char* const Ab0 = smem;
    char* const Bb0 = smem + 65536;

    const int tid = threadIdx.x;
    const int lane = tid & 63;
    const int wv = tid >> 6;               // 0..7
    const int wr = wv >> 2, wc = wv & 3;   // 2 x 4 wave grid
    const int brow = blockIdx.x * 128;

    // staging sources: A chunk c (c=0,1): plane=c, sub=wv
    //   row = wv*16 + (lane&15), k = (lane>>4)*8 + c*4   (4 f32 = 16B)
    // B chunk c: ci = wv + c*8, col = ci*16 + (lane&15), k = (lane>>4)*8 (8 bf16)
    const char* asrc[2];
    int adst[2];
#pragma unroll
    for (int c = 0; c < 2; ++c) {
        int ar = brow + wv * 16 + (lane & 15); if (ar > M - 1) ar = M - 1;
        int k = (lane >> 4) * 8 + c * 4;
        asrc[c] = (const char*)&X[(size_t)ar * NFEAT + k];
        adst[c] = (wv + c * 8) * 1024;
    }
    const char* bsrc[2];
    int bdst[2];
#pragma unroll
    for (int c = 0; c < 2; ++c) {
        int ci = wv + c * 8;
        int col = ci * 16 + (lane & 15);
        bsrc[c] = (const char*)&W1t[(size_t)col * NFEAT + (lane >> 4) * 8];
        bdst[c] = ci * 1024;
    }

    f32x4 acc[4][4];
#pragma unroll
    for (int m = 0; m < 4; ++m)
#pragma unroll
        for (int n = 0; n < 4; ++n) acc[m][n] = f32x4{0.f, 0.f, 0.f, 0.f};

    auto stage = [&](int buf, int step) {
#pragma unroll
        for (int c = 0; c < 2; ++c)
            gload_lds16(asrc[c] + (size_t)step * 128, Ab0 + buf * 16384 + adst[c]);
#pragma unroll
        for (int c = 0; c < 2; ++c)
            gload_lds16(bsrc[c] + (size_t)step * 64, Bb0 + buf * 16384 + bdst[c]);
    };

    constexpr int NSTEP = NFEAT / 32;      // 16
    stage(0, 0);
    stage(1, 1);

    for (int s = 0; s < NSTEP; ++s) {
        if (s + 2 < NSTEP) {
            stage((s + 2) & 3, s + 2);
            asm volatile("s_waitcnt vmcnt(8)" ::: "memory");
        } else if (s + 1 < NSTEP) {
            asm volatile("s_waitcnt vmcnt(4)" ::: "memory");
        } else {
            asm volatile("s_waitcnt vmcnt(0)" ::: "memory");
        }
        __builtin_amdgcn_s_barrier();
        asm volatile("" ::: "memory");

        const char* Abuf = Ab0 + (s & 3) * 16384;
        const char* Bbuf = Bb0 + (s & 3) * 16384;
        short8v a[4], b[4];
#pragma unroll
        for (int m = 0; m < 4; ++m) {
            int g = ((wr * 4 + m) * 64 + lane) * 16;
            f32x4 lo = *(const f32x4*)(Abuf + g);
            f32x4 hi = *(const f32x4*)(Abuf + 8192 + g);
            uint4 u;
            u.x = cvtpk2(lo[0], lo[1]); u.y = cvtpk2(lo[2], lo[3]);
            u.z = cvtpk2(hi[0], hi[1]); u.w = cvtpk2(hi[2], hi[3]);
            a[m] = __builtin_bit_cast(short8v, u);
        }
#pragma unroll
        for (int n = 0; n < 4; ++n)
            b[n] = *(const short8v*)(Bbuf + ((wc * 4 + n) * 64 + lane) * 16);
#pragma unroll
        for (int m = 0; m < 4; ++m)
#pragma unroll
            for (int n = 0; n < 4; ++n)
                acc[m][n] = __builtin_amdgcn_mfma_f32_16x16x32_bf16(a[m], b[n], acc[m][n], 0, 0, 0);

        __builtin_amdgcn_s_barrier();      // protect buf reuse (writer is 3 bufs ahead)
        asm volatile("" ::: "memory");
    }

#pragma unroll
    for (int n = 0; n < 4; ++n) {
        int colg = wc * 64 + n * 16 + (lane & 15);
        float bv = b1[colg];
#pragma unroll
        for (int m = 0; m < 4; ++m) {
#pragma unroll
            for (int r = 0; r < 4; ++r) {
                int rowg = brow + wr * 64 + m * 16 + (lane >> 4) * 4 + r;
                if (rowg < M) {
                    float v = fmaxf(acc[m][n][r] + bv, 0.f);
                    Hb[(size_t)rowg * NHID + colg] = f2bf(v);
                }
            }
        }
    }
}

// ---------------------------------------------------------------------------
// GEMM layer 2, same pipeline: C0[M][128] = Hb[M][256] @ W2t[128][256]^T + b2
// Tile 128x128, 256 threads (4 waves, 2x2), BK=32, NBUF=4, depth-2, bf16 A.
// Per-wave loads/stage = 4 -> vmcnt(8)/(4)/(0). LDS 64KB -> 2 blocks/CU.
// ---------------------------------------------------------------------------
__global__ __launch_bounds__(256) void gemm2_pipe(const unsigned short* __restrict__ Hb,
                                                  const unsigned short* __restrict__ W2t,
                                                  const float* __restrict__ b2,
                                                  unsigned short* __restrict__ C0, int M) {
    __shared__ char smem[65536];           // 4x8KB A + 4x8KB B
    char* const Ab0 = smem;
    char* const Bb0 = smem + 32768;

    const int tid = threadIdx.x;
    const int lane = tid & 63;
    const int wv = tid >> 6;               // 0..3
    const int wr = wv >> 1, wc = wv & 1;
    const int brow = blockIdx.x * 128;

    const char* asrc[2];
    const char* bsrc[2];
    int adst[2], bdst[2];
#pragma unroll
    for (int c = 0; c < 2; ++c) {
        int ci = wv + c * 4;               // 0..7
        int ar = brow + ci * 16 + (lane & 15); if (ar > M - 1) ar = M - 1;
        asrc[c] = (const char*)&Hb[(size_t)ar * NHID + (lane >> 4) * 8];
        adst[c] = ci * 1024;
        int col = ci * 16 + (lane & 15);
        bsrc[c] = (const char*)&W2t[(size_t)col * NHID + (lane >> 4) * 8];
        bdst[c] = ci * 1024;
    }

    f32x4 acc[4][4];
#pragma unroll
    for (int m = 0; m < 4; ++m)
#pragma unroll
        for (int n = 0; n < 4; ++n) acc[m][n] = f32x4{0.f, 0.f, 0.f, 0.f};

    auto stage = [&](int buf, int step) {
#pragma unroll
        for (int c = 0; c < 2; ++c)
            gload_lds16(asrc[c] + (size_t)step * 64, Ab0 + buf * 8192 + adst[c]);
#pragma unroll
        for (int c = 0; c < 2; ++c)
            gload_lds16(bsrc[c] + (size_t)step * 64, Bb0 + buf * 8192 + bdst[c]);
    };

    constexpr int NSTEP = NHID / 32;       // 8
    stage(0, 0);
    stage(1, 1);

    for (int s = 0; s < NSTEP; ++s) {
        if (s + 2 < NSTEP) {
            stage((s + 2) & 3, s + 2);
            asm volatile("s_waitcnt vmcnt(8)" ::: "memory");
        } else if (s + 1 < NSTEP) {
            asm volatile("s_waitcnt vmcnt(4)" ::: "memory");
        } else {
            asm volatile("s_waitcnt vmcnt(0)" ::: "memory");
        }
        __builtin_amdgcn_s_barrier();
        asm volatile("" ::: "memory");

        const char* Abuf = Ab0 + (s & 3) * 8192;
        const char* Bbuf = Bb0 + (s & 3) * 8192;
        short8v a[4], b[4];
#pragma unroll
        for (int m = 0; m < 4; ++m)
            a[m] = *(const short8v*)(Abuf + ((wr * 4 + m) * 64 + lane) * 16);
#pragma unroll
        for (int n = 0; n < 4; ++n)
            b[n] = *(const short8v*)(Bbuf + ((wc * 4 + n) * 64 + lane) * 16);
#pragma unroll
        for (int m = 0; m < 4; ++m)
#pragma unroll
            for (int n = 0; n < 4; ++n)
                acc[m][n] = __builtin_amdgcn_mfma_f32_16x16x32_bf16(a[m], b[n], acc[m][n], 0, 0, 0);

        __builtin_amdgcn_s_barrier();
        asm volatile("" ::: "memory");
    }

#pragma unroll
    for (int n = 0; n < 4; ++n) {
        int colg = wc * 64 + n * 16 + (lane & 15);
        float bv = b2[colg];
#pragma unroll
        for (int m = 0; m < 4; ++m) {
#pragma unroll
            for (int r = 0; r < 4; ++r) {
                int rowg = brow + wr * 64 + m * 16 + (lane >> 4) * 4 + r;
                if (rowg < M)
                    C0[(size_t)rowg * NCLASS + colg] = f2bf(acc[m][n][r] + bv);
            }
        }
    }
}

// ---------------------------------------------------------------------------
// One propagation hop (pull over CSR-by-dst), bf16 carry, packed int2 edges.
// One wave per node; lanes preload up to 64 edges' metadata (one 8B load),
// broadcast via readlane. Unroll 8 for deep memory-level parallelism.
// FINAL=1: fuse log-softmax, write f32 to outf.
// ---------------------------------------------------------------------------
template<int FINAL>
__global__ __launch_bounds__(256) void hop_kernel(const unsigned short* __restrict__ carry,
                                                  const unsigned short* __restrict__ c0,
                                                  const int* __restrict__ rp,
                                                  const int2* __restrict__ epk,
                                                  unsigned short* __restrict__ outb,
                                                  float* __restrict__ outf, int nnodes) {
    int node = blockIdx.x * 4 + (threadIdx.x >> 6);
    if (node >= nnodes) return;
    int lane = threadIdx.x & 63;
    int e0 = rp[node], e1 = rp[node + 1];

    float a0x = 0.f, a0y = 0.f, a1x = 0.f, a1y = 0.f;
    float a2x = 0.f, a2y = 0.f, a3x = 0.f, a3y = 0.f;

    for (int eb = e0; eb < e1; eb += 64) {
        int nb = e1 - eb; if (nb > 64) nb = 64;
        int cs = 0, wvi = 0;
        if (lane < nb) {
            int2 m = epk[eb + lane];
            cs = m.x; wvi = m.y;
        }
        int j = 0;
        for (; j + 7 < nb; j += 8) {
            int s0 = __builtin_amdgcn_readlane(cs, j);
            int s1 = __builtin_amdgcn_readlane(cs, j + 1);
            int s2 = __builtin_amdgcn_readlane(cs, j + 2);
            int s3 = __builtin_amdgcn_readlane(cs, j + 3);
            int s4 = __builtin_amdgcn_readlane(cs, j + 4);
            int s5 = __builtin_amdgcn_readlane(cs, j + 5);
            int s6 = __builtin_amdgcn_readlane(cs, j + 6);
            int s7 = __builtin_amdgcn_readlane(cs, j + 7);
            float w0 = __builtin_bit_cast(float, __builtin_amdgcn_readlane(wvi, j));
            float w1 = __builtin_bit_cast(float, __builtin_amdgcn_readlane(wvi, j + 1));
            float w2 = __builtin_bit_cast(float, __builtin_amdgcn_readlane(wvi, j + 2));
            float w3 = __builtin_bit_cast(float, __builtin_amdgcn_readlane(wvi, j + 3));
            float w4 = __builtin_bit_cast(float, __builtin_amdgcn_readlane(wvi, j + 4));
            float w5 = __builtin_bit_cast(float, __builtin_amdgcn_readlane(wvi, j + 5));
            float w6 = __builtin_bit_cast(float, __builtin_amdgcn_readlane(wvi, j + 6));
            float w7 = __builtin_bit_cast(float, __builtin_amdgcn_readlane(wvi, j + 7));
            unsigned u0 = ((const unsigned*)(carry + ((size_t)s0 << 7)))[lane];
            unsigned u1 = ((const unsigned*)(carry + ((size_t)s1 << 7)))[lane];
            unsigned u2 = ((const unsigned*)(carry + ((size_t)s2 << 7)))[lane];
            unsigned u3 = ((const unsigned*)(carry + ((size_t)s3 << 7)))[lane];
            unsigned u4 = ((const unsigned*)(carry + ((size_t)s4 << 7)))[lane];
            unsigned u5 = ((const unsigned*)(carry + ((size_t)s5 << 7)))[lane];
            unsigned u6 = ((const unsigned*)(carry + ((size_t)s6 << 7)))[lane];
            unsigned u7 = ((const unsigned*)(carry + ((size_t)s7 << 7)))[lane];
            a0x = fmaf(w0, bflo(u0), a0x); a0y = fmaf(w0, bfhi(u0), a0y);
            a1x = fmaf(w1, bflo(u1), a1x); a1y = fmaf(w1, bfhi(u1), a1y);
            a2x = fmaf(w2, bflo(u2), a2x); a2y = fmaf(w2, bfhi(u2), a2y);
            a3x = fmaf(w3, bflo(u3), a3x); a3y = fmaf(w3, bfhi(u3), a3y);
            a0x = fmaf(w4, bflo(u4), a0x); a0y = fmaf(w4, bfhi(u4), a0y);
            a1x = fmaf(w5, bflo(u5), a1x); a1y = fmaf(w5, bfhi(u5), a1y);
            a2x = fmaf(w6, bflo(u6), a2x); a2y = fmaf(w6, bfhi(u6), a2y);
            a3x = fmaf(w7, bflo(u7), a3x); a3y = fmaf(w7, bfhi(u7), a3y);
        }
        for (; j + 3 < nb; j += 4) {
            int s0 = __builtin_amdgcn_readlane(cs, j);
            int s1 = __builtin_amdgcn_readlane(cs, j + 1);
            int s2 = __builtin_amdgcn_readlane(cs, j + 2);
            int s3 = __builtin_amdgcn_readlane(cs, j + 3);
            float w0 = __builtin_bit_cast(float, __builtin_amdgcn_readlane(wvi, j));
            float w1 = __builtin_bit_cast(float, __builtin_amdgcn_readlane(wvi, j + 1));
            float w2 = __builtin_bit_cast(float, __builtin_amdgcn_readlane(wvi, j + 2));
            float w3 = __builtin_bit_cast(float, __builtin_amdgcn_readlane(wvi, j + 3));
            unsigned u0 = ((const unsigned*)(carry + ((size_t)s0 << 7)))[lane];
            unsigned u1 = ((const unsigned*)(carry + ((size_t)s1 << 7)))[lane];
            unsigned u2 = ((const unsigned*)(carry + ((size_t)s2 << 7)))[lane];
            unsigned u3 = ((const unsigned*)(carry + ((size_t)s3 << 7)))[lane];
            a0x = fmaf(w0, bflo(u0), a0x); a0y = fmaf(w0, bfhi(u0), a0y);
            a1x = fmaf(w1, bflo(u1), a1x); a1y = fmaf(w1, bfhi(u1), a1y);
            a2x = fmaf(w2, bflo(u2), a2x); a2y = fmaf(w2, bfhi(u2), a2y);
            a3x = fmaf(w3, bflo(u3), a3x); a3y = fmaf(w3, bfhi(u3), a3y);
        }
        for (; j < nb; ++j) {
            int s0 = __builtin_amdgcn_readlane(cs, j);
            float w0 = __builtin_bit_cast(float, __builtin_amdgcn_readlane(wvi, j));
            unsigned u0 = ((const unsigned*)(carry + ((size_t)s0 << 7)))[lane];
            a0x = fmaf(w0, bflo(u0), a0x); a0y = fmaf(w0, bfhi(u0), a0y);
        }
    }

    unsigned ux = ((const unsigned*)(c0 + ((size_t)node << 7)))[lane];
    float vx = (1.f - ALPHA) * (a0x + a1x + a2x + a3x) + ALPHA * bflo(ux);
    float vy = (1.f - ALPHA) * (a0y + a1y + a2y + a3y) + ALPHA * bfhi(ux);

    if (FINAL) {
        float mx = fmaxf(vx, vy);
#pragma unroll
        for (int off = 32; off; off >>= 1) mx = fmaxf(mx, __shfl_xor(mx, off, 64));
        float se = __expf(vx - mx) + __expf(vy - mx);
#pragma unroll
        for (int off = 32; off; off >>= 1) se += __shfl_xor(se, off, 64);
        float l = mx + __logf(se);
        float2 o; o.x = vx - l; o.y = vy - l;
        ((float2*)(outf + ((size_t)node << 7)))[lane] = o;
    } else {
        unsigned o = (unsigned)f2bf(vx) | ((unsigned)f2bf(vy) << 16);
        ((unsigned*)(outb + ((size_t)node << 7)))[lane] = o;
    }
}

// ---------------------------------------------------------------------------

extern "C" void kernel_launch(void* const* d_in, const int* in_sizes, int n_in,
                              void* d_out, int out_size, void* d_ws, size_t ws_size,
                              hipStream_t stream) {
    const float* x   = (const float*)d_in[0];
    const int*   ei  = (const int*)d_in[1];
    const float* ew  = (const float*)d_in[2];
    const float* W1  = (const float*)d_in[3];
    const float* b1  = (const float*)d_in[4];
    const float* W2  = (const float*)d_in[5];
    const float* b2  = (const float*)d_in[6];
    float* outp = (float*)d_out;

    const int E = in_sizes[1] / 2;
    const int Nn = N_NODES;
    const int* srcv = ei;
    const int* dstv = ei + E;
    const size_t NC = (size_t)Nn * NCLASS;   // 12.8M elements

    // workspace layout (16B-aligned buffers)
    unsigned short* c0  = (unsigned short*)d_ws;    // bf16 x0 copy     [NC]
    unsigned short* A16 = c0 + NC;                  // ping             [NC]
    unsigned short* B16 = A16 + NC;                 // pong             [NC]
    unsigned short* hb  = A16;                      // H bf16 overlay (Nn*NHID = 2*NC, dead before hops)
    unsigned short* w1t = B16 + NC;                 // 256x512
    unsigned short* w2t = w1t + NHID * NFEAT;       // 128x256
    int* row_ptr = (int*)(w2t + NCLASS * NHID);     // Nn+1
    int* fill    = row_ptr + (Nn + 1);              // Nn (counts)
    int* partial = fill + Nn;                       // 128
    int2* epk    = (int2*)(partial + 128);          // E packed {src, w}

    const int NB = (Nn + 1023) / 1024;              // 98 scan blocks

    // ---- CSR build ----
    hipMemsetAsync(fill, 0, (size_t)Nn * sizeof(int), stream);
    count_kernel<<<(E + 255) / 256, 256, 0, stream>>>(dstv, fill, E);
    scan_p1<<<NB, 256, 0, stream>>>(fill, partial, Nn);
    scan_p2<<<1, 128, 0, stream>>>(partial, NB);
    scan_p3<<<NB, 256, 0, stream>>>(fill, partial, row_ptr, fill, Nn);
    scatter_kernel<<<(E + 255) / 256, 256, 0, stream>>>(srcv, dstv, ew, fill, epk, E);

    // ---- weight prep ----
    wtrans_kernel<<<(NHID * NFEAT + 255) / 256, 256, 0, stream>>>(W1, w1t, NFEAT, NHID);
    wtrans_kernel<<<(NCLASS * NHID + 255) / 256, 256, 0, stream>>>(W2, w2t, NHID, NCLASS);

    // ---- MLP (bf16 MFMA, depth-2 counted-vmcnt pipeline) ----
    {
        int gm = (Nn + 127) / 128;                  // 782
        gemm1_pipe<<<gm, 512, 0, stream>>>(x, w1t, b1, hb, Nn);
        gemm2_pipe<<<gm, 256, 0, stream>>>(hb, w2t, b2, c0, Nn);
    }

    // ---- K_HOPS propagation (bf16 carry), ping-pong; last hop fuses softmax ----
    int grid = (Nn + 3) / 4;
    const unsigned short* carry = c0;
    unsigned short* dsts[2] = {A16, B16};
    for (int k = 0; k < K_HOPS - 1; ++k) {
        unsigned short* o = dsts[k & 1];
        hop_kernel<0><<<grid, 256, 0, stream>>>(carry, c0, row_ptr, epk, o, nullptr, Nn);
        carry = o;
    }
    hop_kernel<1><<<grid, 256, 0, stream>>>(carry, c0, row_ptr, epk, nullptr, outp, Nn);
}